// Round 15
// baseline (167.347 us; speedup 1.0000x reference)
//
#include <hip/hip_runtime.h>
#include <hip/hip_bf16.h>
#include <math.h>

#define Vv   32
#define Dd   128
#define Hh   8
#define Bb   8
#define Mm   2048
#define BM   (Bb*Mm)        // 16384
#define NEL  (BM*Dd)        // 2097152
#define XNS  140            // LDS stride (halves) for 128-col tiles, bank-padded
#define QKS  396            // LDS stride (halves) for 384-col qkv tile, bank-padded

typedef _Float16 half4_t __attribute__((ext_vector_type(4)));
typedef _Float16 half8_t __attribute__((ext_vector_type(8)));
typedef __fp16   fp16x2  __attribute__((ext_vector_type(2)));
typedef float    float4_t __attribute__((ext_vector_type(4)));
#define MFMA16 __builtin_amdgcn_mfma_f32_16x16x16f16

#if __has_builtin(__builtin_amdgcn_exp2f)
__device__ __forceinline__ float fexp2(float x) { return __builtin_amdgcn_exp2f(x); }
#else
__device__ __forceinline__ float fexp2(float x) { return __expf(x * 0.6931471805599453f); }
#endif

// ---------------- front: [blocks 0..1039] weights->blocked f16 + RoPE tables;
//                  [blocks 1040..3087] embedding gather -> f16 + ssq partials ----------------
__global__ __launch_bounds__(256) void front_kernel(const float* __restrict__ Wq,
                                                    const float* __restrict__ Wk,
                                                    const float* __restrict__ Wv,
                                                    const float* __restrict__ in_w,
                                                    const float* __restrict__ out_pw,
                                                    const float* __restrict__ lin_w,
                                                    const float* __restrict__ out_w,
                                                    _Float16* __restrict__ Wh,
                                                    float* __restrict__ cosT,
                                                    float* __restrict__ sinT,
                                                    const int* __restrict__ idx,
                                                    const float* __restrict__ emb,
                                                    _Float16* __restrict__ Xh,
                                                    float* __restrict__ partials) {
    __shared__ float wsum[4];
    if (blockIdx.x < 1040) {
        int gid = blockIdx.x * 256 + threadIdx.x;       // 266240 slots
        if (gid < 135168) {
            const float* src;
            int i;
            if (gid < 131072) {
                int seg = gid >> 14; i = gid & 16383;
                src = seg == 0 ? Wq : seg == 1 ? Wk : seg == 2 ? Wv :
                      seg < 6 ? in_w + (size_t)(seg - 3) * 16384 :
                      seg == 6 ? out_pw : lin_w;
            } else { src = out_w; i = gid - 131072; }   // out_w: 32x128 -> 16 tiles
            int tile = i >> 8, within = i & 255;
            int nt = tile >> 3, kk = tile & 7;
            int r = within >> 4, cc = within & 15;
            Wh[gid] = (_Float16)src[(nt * 16 + r) * 128 + kk * 16 + cc];
        } else {
            int rid = gid - 135168;                     // Mm*64 = 131072
            int i = rid & 63, m = rid >> 6;
            float ex = -2.0f * ((float)i - 1.0f) / 128.0f;
            float basef = expf(ex * 9.210340371976184f);
            float ang = (float)m * basef;
            cosT[rid] = cosf(ang);
            sinT[rid] = sinf(ang);
        }
    } else {
        int blk = blockIdx.x - 1040;                    // 0..2047
        int gid = blk * 256 + threadIdx.x;              // NEL/4
        int token = gid >> 5, t4 = gid & 31;
        float4 x = *(const float4*)(emb + (size_t)idx[token] * 128 + t4 * 4);
        half4_t o;
        o[0] = (_Float16)x.x; o[1] = (_Float16)x.y; o[2] = (_Float16)x.z; o[3] = (_Float16)x.w;
        *(half4_t*)(Xh + (size_t)gid * 4) = o;
        float v = x.x * x.x + x.y * x.y + x.z * x.z + x.w * x.w;
        #pragma unroll
        for (int off = 32; off; off >>= 1) v += __shfl_xor(v, off);
        int lane = threadIdx.x & 63, wave = threadIdx.x >> 6;
        if (lane == 0) wsum[wave] = v;
        __syncthreads();
        if (threadIdx.x == 0) partials[blk] = wsum[0] + wsum[1] + wsum[2] + wsum[3];
    }
}

// ---------------- FUSED: ssq-reduce + normscale + QKV proj + RoPE + in_proj -> Qp/Kp/Vp ----------------
__global__ __launch_bounds__(256) void gemm_qkvproj_kernel(const _Float16* __restrict__ xh,
                                                           const float* __restrict__ scale,
                                                           const float* __restrict__ part1,
                                                           const _Float16* __restrict__ Whqkv,
                                                           const _Float16* __restrict__ Whin,
                                                           const float* __restrict__ in_b,
                                                           const float* __restrict__ cosT,
                                                           const float* __restrict__ sinT,
                                                           _Float16* __restrict__ xnh,
                                                           _Float16* __restrict__ Qp,
                                                           _Float16* __restrict__ Kp,
                                                           _Float16* __restrict__ Vp) {
    __shared__ _Float16 xn[32 * XNS];
    __shared__ _Float16 qkv[32 * QKS];
    __shared__ float wsum0[4];
    int tid = threadIdx.x;
    int row0 = blockIdx.x * 32;
    {
        float v = part1[(row0 >> 11) * 256 + tid];
        #pragma unroll
        for (int off = 32; off; off >>= 1) v += __shfl_xor(v, off);
        if ((tid & 63) == 0) wsum0[tid >> 6] = v;
    }
    __syncthreads();
    float iv = 512.0f / sqrtf(wsum0[0] + wsum0[1] + wsum0[2] + wsum0[3]);
    {
        #pragma unroll
        for (int it = 0; it < 2; it++) {
            int idx = tid + it * 256;
            int rw = idx >> 4, c8 = (idx & 15) * 8;
            int m = (row0 + rw) & (Mm - 1);
            half8_t x8 = *(const half8_t*)(xh + (size_t)(row0 + rw) * 128 + c8);
            const float* sp = scale + (size_t)m * 128 + c8;
            float4 s0 = *(const float4*)sp;
            float4 s1 = *(const float4*)(sp + 4);
            half8_t o8;
            o8[0] = (_Float16)((float)x8[0] * iv * s0.x);
            o8[1] = (_Float16)((float)x8[1] * iv * s0.y);
            o8[2] = (_Float16)((float)x8[2] * iv * s0.z);
            o8[3] = (_Float16)((float)x8[3] * iv * s0.w);
            o8[4] = (_Float16)((float)x8[4] * iv * s1.x);
            o8[5] = (_Float16)((float)x8[5] * iv * s1.y);
            o8[6] = (_Float16)((float)x8[6] * iv * s1.z);
            o8[7] = (_Float16)((float)x8[7] * iv * s1.w);
            *(half8_t*)(xn + rw * XNS + c8) = o8;
            *(half8_t*)(xnh + (size_t)(row0 + rw) * 128 + c8) = o8;
        }
    }
    __syncthreads();
    int wave = tid >> 6, lane = tid & 63;
    int r = lane & 15, c = lane >> 4;
    int lofs = r * 16 + 4 * c;
    int nb = wave * 96;
    int nb16 = wave * 6;
    {
        half4_t af[2][8];
        #pragma unroll
        for (int rt = 0; rt < 2; rt++)
            #pragma unroll
            for (int kk = 0; kk < 8; kk++)
                af[rt][kk] = *(const half4_t*)(xn + (rt * 16 + r) * XNS + kk * 16 + 4 * c);
        float4_t acc[2][6];
        #pragma unroll
        for (int rt = 0; rt < 2; rt++)
            #pragma unroll
            for (int t = 0; t < 6; t++) acc[rt][t] = (float4_t){0.f, 0.f, 0.f, 0.f};
        #pragma unroll
        for (int kk = 0; kk < 8; kk++) {
            half4_t wf[6];
            #pragma unroll
            for (int t = 0; t < 6; t++)
                wf[t] = *(const half4_t*)(Whqkv + ((nb16 + t) * 8 + kk) * 256 + lofs);
            #pragma unroll
            for (int t = 0; t < 6; t++) {
                acc[0][t] = MFMA16(af[0][kk], wf[t], acc[0][t], 0, 0, 0);
                acc[1][t] = MFMA16(af[1][kk], wf[t], acc[1][t], 0, 0, 0);
            }
        }
        #pragma unroll
        for (int rt = 0; rt < 2; rt++) {
            #pragma unroll
            for (int t = 0; t < 6; t++) {
                int n = nb + t * 16 + r;
                int ci = (n & 127) >> 1;
                #pragma unroll
                for (int reg = 0; reg < 4; reg++) {
                    int m2 = (row0 + rt * 16 + 4 * c + reg) & (Mm - 1);
                    float v = acc[rt][t][reg];
                    float vp = __shfl_xor(v, 1);     // pair column n^1 lives in lane^1
                    float cs = cosT[m2 * 64 + ci], sn = sinT[m2 * 64 + ci];
                    v = (n & 1) ? (-vp * sn + v * cs) : (v * cs + vp * sn);
                    qkv[(rt * 16 + 4 * c + reg) * QKS + n] = (_Float16)v;
                }
            }
        }
    }
    __syncthreads();
    {
        int seg_lo = nb >> 7;
        int seg_hi = (nb + 80) >> 7;
        half4_t aql[2][8], aqh[2][8];
        #pragma unroll
        for (int rt = 0; rt < 2; rt++)
            #pragma unroll
            for (int kk = 0; kk < 8; kk++) {
                aql[rt][kk] = *(const half4_t*)(qkv + (rt * 16 + r) * QKS + seg_lo * 128 + kk * 16 + 4 * c);
                aqh[rt][kk] = *(const half4_t*)(qkv + (rt * 16 + r) * QKS + seg_hi * 128 + kk * 16 + 4 * c);
            }
        float4_t acc[2][6];
        #pragma unroll
        for (int rt = 0; rt < 2; rt++)
            #pragma unroll
            for (int t = 0; t < 6; t++) acc[rt][t] = (float4_t){0.f, 0.f, 0.f, 0.f};
        #pragma unroll
        for (int kk = 0; kk < 8; kk++) {
            half4_t wf[6];
            #pragma unroll
            for (int t = 0; t < 6; t++) {
                int colg = nb + t * 16;
                int seg = colg >> 7;
                int ntl = (colg & 127) >> 4;
                wf[t] = *(const half4_t*)(Whin + ((seg * 8 + ntl) * 8 + kk) * 256 + lofs);
            }
            #pragma unroll
            for (int t = 0; t < 6; t++) {
                int seg = (nb + t * 16) >> 7;
                acc[0][t] = MFMA16(seg == seg_lo ? aql[0][kk] : aqh[0][kk], wf[t], acc[0][t], 0, 0, 0);
                acc[1][t] = MFMA16(seg == seg_lo ? aql[1][kk] : aqh[1][kk], wf[t], acc[1][t], 0, 0, 0);
            }
        }
        int bb = row0 >> 11;
        #pragma unroll
        for (int rt = 0; rt < 2; rt++) {
            int t16 = ((row0 + rt * 16) & 2047) >> 4;
            #pragma unroll
            for (int t = 0; t < 6; t++) {
                int colg = nb + t * 16;
                int seg = colg >> 7;
                int h = (colg & 127) >> 4;
                size_t tb = ((size_t)(bb * 8 + h) * 128 + t16) * 256;
                float bv = in_b[colg + r];
                _Float16* dst = seg == 0 ? Qp : seg == 1 ? Kp : Vp;
                #pragma unroll
                for (int reg = 0; reg < 4; reg++) {
                    float v = acc[rt][t][reg] + bv;
                    int key = 4 * c + reg;
                    if (seg < 2) dst[tb + key * 16 + r] = (_Float16)v;   // [token][d=r]
                    else         dst[tb + r * 16 + key] = (_Float16)v;   // [d=r][token]
                }
            }
        }
    }
}

// ---------------- out_proj: Oh f16 @ W^T + bias + resid(xnh) -> xresh f16, ssq partials ----------------
__global__ __launch_bounds__(256) void gemm_ep1_kernel(const _Float16* __restrict__ Oh,
                                                       const _Float16* __restrict__ W6,
                                                       const float* __restrict__ bias,
                                                       const _Float16* __restrict__ xnh,
                                                       _Float16* __restrict__ xresh,
                                                       float* __restrict__ partials) {
    __shared__ _Float16 At[32 * XNS];
    int tid = threadIdx.x;
    int row0 = blockIdx.x * 32;
    #pragma unroll
    for (int it = 0; it < 2; it++) {
        int idx = tid + it * 256;
        int rw = idx >> 4, c8 = (idx & 15) * 8;
        *(half8_t*)(At + rw * XNS + c8) = *(const half8_t*)(Oh + (size_t)(row0 + rw) * 128 + c8);
    }
    __syncthreads();
    int wave = tid >> 6, lane = tid & 63;
    int r = lane & 15, c = lane >> 4;
    int lofs = r * 16 + 4 * c;
    int n0 = wave * 32;
    half4_t af[2][8];
    #pragma unroll
    for (int rt = 0; rt < 2; rt++)
        #pragma unroll
        for (int kk = 0; kk < 8; kk++)
            af[rt][kk] = *(const half4_t*)(At + (rt * 16 + r) * XNS + kk * 16 + 4 * c);
    float4_t acc[2][2];
    #pragma unroll
    for (int rt = 0; rt < 2; rt++) {
        acc[rt][0] = (float4_t){0.f, 0.f, 0.f, 0.f};
        acc[rt][1] = (float4_t){0.f, 0.f, 0.f, 0.f};
    }
    #pragma unroll
    for (int kk = 0; kk < 8; kk++) {
        half4_t wf[2];
        wf[0] = *(const half4_t*)(W6 + ((wave * 2 + 0) * 8 + kk) * 256 + lofs);
        wf[1] = *(const half4_t*)(W6 + ((wave * 2 + 1) * 8 + kk) * 256 + lofs);
        #pragma unroll
        for (int t = 0; t < 2; t++) {
            acc[0][t] = MFMA16(af[0][kk], wf[t], acc[0][t], 0, 0, 0);
            acc[1][t] = MFMA16(af[1][kk], wf[t], acc[1][t], 0, 0, 0);
        }
    }
    float lssq = 0.f;
    #pragma unroll
    for (int rt = 0; rt < 2; rt++) {
        #pragma unroll
        for (int t = 0; t < 2; t++) {
            int n = n0 + t * 16 + r;
            float bv = bias[n];
            #pragma unroll
            for (int reg = 0; reg < 4; reg++) {
                int row = row0 + rt * 16 + 4 * c + reg;
                float v = acc[rt][t][reg] + bv + (float)xnh[(size_t)row * 128 + n];
                lssq += v * v;
                xresh[(size_t)row * 128 + n] = (_Float16)v;
            }
        }
    }
    #pragma unroll
    for (int off = 32; off; off >>= 1) lssq += __shfl_xor(lssq, off);
    __shared__ float wsum[4];
    if (lane == 0) wsum[wave] = lssq;
    __syncthreads();
    if (tid == 0) partials[blockIdx.x] = wsum[0] + wsum[1] + wsum[2] + wsum[3];
}

// ---------------- FUSED FFN: ssq-reduce + normscale(xresh) + GEMM + relu + resid -> ffoh f16 ----------------
__global__ __launch_bounds__(256) void gemm_ep2_kernel(const _Float16* __restrict__ xresh,
                                                       const float* __restrict__ scale,
                                                       const float* __restrict__ part2,
                                                       const _Float16* __restrict__ W7,
                                                       const float* __restrict__ bias,
                                                       _Float16* __restrict__ ffoh) {
    __shared__ _Float16 At[32 * XNS];
    int tid = threadIdx.x;
    int row0 = blockIdx.x * 32;
    float pv = part2[(row0 >> 11) * 64 + (tid & 63)];
    #pragma unroll
    for (int off = 32; off; off >>= 1) pv += __shfl_xor(pv, off);
    float iv = 512.0f / sqrtf(pv);
    #pragma unroll
    for (int it = 0; it < 2; it++) {
        int idx = tid + it * 256;
        int rw = idx >> 4, c8 = (idx & 15) * 8;
        int m = (row0 + rw) & (Mm - 1);
        half8_t x8 = *(const half8_t*)(xresh + (size_t)(row0 + rw) * 128 + c8);
        const float* sp = scale + (size_t)m * 128 + c8;
        float4 s0 = *(const float4*)sp;
        float4 s1 = *(const float4*)(sp + 4);
        half8_t o8;
        o8[0] = (_Float16)((float)x8[0] * iv * s0.x);
        o8[1] = (_Float16)((float)x8[1] * iv * s0.y);
        o8[2] = (_Float16)((float)x8[2] * iv * s0.z);
        o8[3] = (_Float16)((float)x8[3] * iv * s0.w);
        o8[4] = (_Float16)((float)x8[4] * iv * s1.x);
        o8[5] = (_Float16)((float)x8[5] * iv * s1.y);
        o8[6] = (_Float16)((float)x8[6] * iv * s1.z);
        o8[7] = (_Float16)((float)x8[7] * iv * s1.w);
        *(half8_t*)(At + rw * XNS + c8) = o8;
    }
    __syncthreads();
    int wave = tid >> 6, lane = tid & 63;
    int r = lane & 15, c = lane >> 4;
    int lofs = r * 16 + 4 * c;
    int n0 = wave * 32;
    half4_t af[2][8];
    #pragma unroll
    for (int rt = 0; rt < 2; rt++)
        #pragma unroll
        for (int kk = 0; kk < 8; kk++)
            af[rt][kk] = *(const half4_t*)(At + (rt * 16 + r) * XNS + kk * 16 + 4 * c);
    float4_t acc[2][2];
    #pragma unroll
    for (int rt = 0; rt < 2; rt++) {
        acc[rt][0] = (float4_t){0.f, 0.f, 0.f, 0.f};
        acc[rt][1] = (float4_t){0.f, 0.f, 0.f, 0.f};
    }
    #pragma unroll
    for (int kk = 0; kk < 8; kk++) {
        half4_t wf[2];
        wf[0] = *(const half4_t*)(W7 + ((wave * 2 + 0) * 8 + kk) * 256 + lofs);
        wf[1] = *(const half4_t*)(W7 + ((wave * 2 + 1) * 8 + kk) * 256 + lofs);
        #pragma unroll
        for (int t = 0; t < 2; t++) {
            acc[0][t] = MFMA16(af[0][kk], wf[t], acc[0][t], 0, 0, 0);
            acc[1][t] = MFMA16(af[1][kk], wf[t], acc[1][t], 0, 0, 0);
        }
    }
    #pragma unroll
    for (int rt = 0; rt < 2; rt++) {
        #pragma unroll
        for (int t = 0; t < 2; t++) {
            int n = n0 + t * 16 + r;
            float bv = bias[n];
            #pragma unroll
            for (int reg = 0; reg < 4; reg++) {
                int row = row0 + rt * 16 + 4 * c + reg;
                float v = fmaxf(acc[rt][t][reg] + bv, 0.f) + (float)xresh[(size_t)row * 128 + n];
                ffoh[(size_t)row * 128 + n] = (_Float16)v;
            }
        }
    }
}

// ---------------- attention helpers (plain-add denominator) ----------------
__device__ __forceinline__ half4_t attn_exps(float4_t st, float& ls) {
    float p0 = fexp2(st[0]), p1 = fexp2(st[1]);
    float p2 = fexp2(st[2]), p3 = fexp2(st[3]);
    ls += (p0 + p1) + (p2 + p3);
    fp16x2 lo = __builtin_amdgcn_cvt_pkrtz(p0, p1);
    fp16x2 hi = __builtin_amdgcn_cvt_pkrtz(p2, p3);
    half4_t pf;
    pf[0] = (_Float16)lo[0]; pf[1] = (_Float16)lo[1];
    pf[2] = (_Float16)hi[0]; pf[3] = (_Float16)hi[1];
    return pf;
}
__device__ __forceinline__ half4_t attn_exps_masked(float4_t st, float& ls, int r, int c) {
    float p0 = (4 * c + 0 <= r) ? fexp2(st[0]) : 0.f;
    float p1 = (4 * c + 1 <= r) ? fexp2(st[1]) : 0.f;
    float p2 = (4 * c + 2 <= r) ? fexp2(st[2]) : 0.f;
    float p3 = (4 * c + 3 <= r) ? fexp2(st[3]) : 0.f;
    ls += (p0 + p1) + (p2 + p3);
    fp16x2 lo = __builtin_amdgcn_cvt_pkrtz(p0, p1);
    fp16x2 hi = __builtin_amdgcn_cvt_pkrtz(p2, p3);
    half4_t pf;
    pf[0] = (_Float16)lo[0]; pf[1] = (_Float16)lo[1];
    pf[2] = (_Float16)hi[0]; pf[3] = (_Float16)hi[1];
    return pf;
}

// ---------------- MFMA flash attention: paired q-tiles + split-K (2 waves/pair), 2-tile unroll ----------------
__global__ __launch_bounds__(256) void attn_kernel(const _Float16* __restrict__ Qp,
                                                   const _Float16* __restrict__ Kp,
                                                   const _Float16* __restrict__ Vp,
                                                   _Float16* __restrict__ Oh) {
    __shared__ float mrg[2][10][64];
    int wave = threadIdx.x >> 6, lane = threadIdx.x & 63;
    int pair = blockIdx.x * 2 + (wave >> 1);         // 0..4095
    int split = wave & 1;
    int qa = pair & 63, bh = pair >> 6, qb = 127 - qa;
    int r = lane & 15, c = lane >> 4;
    int lofs = r * 16 + 4 * c;
    const _Float16* Kb = Kp + (size_t)bh * 32768 + lofs;
    const _Float16* Vb = Vp + (size_t)bh * 32768 + lofs;
    const _Float16* Qb = Qp + (size_t)bh * 32768 + lofs;
    half4_t qfa = *(const half4_t*)(Qb + qa * 256);
    half4_t qfb = *(const half4_t*)(Qb + qb * 256);
    const _Float16 qscale = (_Float16)0.36067376f;   // 0.25 * log2(e)
    qfa *= qscale;
    qfb *= qscale;
    float4_t zero = {0.f, 0.f, 0.f, 0.f};
    float4_t oa = zero, ob = zero;
    float lsa = 0.f, lsb = 0.f;

    // shared range (kt < qa, kt ≡ split mod 2), unrolled by 2 same-parity tiles
    int kt = split;
    for (; kt + 2 < qa; kt += 4) {
        half4_t k0 = *(const half4_t*)(Kb + (size_t)kt * 256);
        half4_t v0 = *(const half4_t*)(Vb + (size_t)kt * 256);
        half4_t k1 = *(const half4_t*)(Kb + (size_t)(kt + 2) * 256);
        half4_t v1 = *(const half4_t*)(Vb + (size_t)(kt + 2) * 256);
        float4_t sa0 = MFMA16(k0, qfa, zero, 0, 0, 0);
        float4_t sb0 = MFMA16(k0, qfb, zero, 0, 0, 0);
        float4_t sa1 = MFMA16(k1, qfa, zero, 0, 0, 0);
        float4_t sb1 = MFMA16(k1, qfb, zero, 0, 0, 0);
        half4_t pa0 = attn_exps(sa0, lsa);
        half4_t pb0 = attn_exps(sb0, lsb);
        half4_t pa1 = attn_exps(sa1, lsa);
        half4_t pb1 = attn_exps(sb1, lsb);
        oa = MFMA16(pa0, v0, oa, 0, 0, 0);
        ob = MFMA16(pb0, v0, ob, 0, 0, 0);
        oa = MFMA16(pa1, v1, oa, 0, 0, 0);
        ob = MFMA16(pb1, v1, ob, 0, 0, 0);
    }
    for (; kt < qa; kt += 2) {
        half4_t k0 = *(const half4_t*)(Kb + (size_t)kt * 256);
        half4_t v0 = *(const half4_t*)(Vb + (size_t)kt * 256);
        float4_t sa = MFMA16(k0, qfa, zero, 0, 0, 0);
        float4_t sb = MFMA16(k0, qfb, zero, 0, 0, 0);
        half4_t pa = attn_exps(sa, lsa);
        half4_t pb = attn_exps(sb, lsb);
        oa = MFMA16(pa, v0, oa, 0, 0, 0);
        ob = MFMA16(pb, v0, ob, 0, 0, 0);
    }
    if ((qa & 1) == split) {                         // tile qa: masked for a, full for b
        half4_t k0 = *(const half4_t*)(Kb + (size_t)qa * 256);
        half4_t v0 = *(const half4_t*)(Vb + (size_t)qa * 256);
        float4_t sa = MFMA16(k0, qfa, zero, 0, 0, 0);
        float4_t sb = MFMA16(k0, qfb, zero, 0, 0, 0);
        half4_t pa = attn_exps_masked(sa, lsa, r, c);
        half4_t pb = attn_exps(sb, lsb);
        oa = MFMA16(pa, v0, oa, 0, 0, 0);
        ob = MFMA16(pb, v0, ob, 0, 0, 0);
    }
    // b-only range (qa < kt < qb, kt ≡ split mod 2), unrolled by 2 same-parity tiles
    {
        int s = qa + 1;
        if ((s & 1) != split) s++;
        int kt2 = s;
        for (; kt2 + 2 < qb; kt2 += 4) {
            half4_t k0 = *(const half4_t*)(Kb + (size_t)kt2 * 256);
            half4_t v0 = *(const half4_t*)(Vb + (size_t)kt2 * 256);
            half4_t k1 = *(const half4_t*)(Kb + (size_t)(kt2 + 2) * 256);
            half4_t v1 = *(const half4_t*)(Vb + (size_t)(kt2 + 2) * 256);
            float4_t sb0 = MFMA16(k0, qfb, zero, 0, 0, 0);
            float4_t sb1 = MFMA16(k1, qfb, zero, 0, 0, 0);
            half4_t pb0 = attn_exps(sb0, lsb);
            half4_t pb1 = attn_exps(sb1, lsb);
            ob = MFMA16(pb0, v0, ob, 0, 0, 0);
            ob = MFMA16(pb1, v1, ob, 0, 0, 0);
        }
        for (; kt2 < qb; kt2 += 2) {
            half4_t k0 = *(const half4_t*)(Kb + (size_t)kt2 * 256);
            half4_t v0 = *(const half4_t*)(Vb + (size_t)kt2 * 256);
            float4_t sb = MFMA16(k0, qfb, zero, 0, 0, 0);
            half4_t pb = attn_exps(sb, lsb);
            ob = MFMA16(pb, v0, ob, 0, 0, 0);
        }
    }
    if ((qb & 1) == split) {                         // tile qb: masked for b
        half4_t k0 = *(const half4_t*)(Kb + (size_t)qb * 256);
        half4_t v0 = *(const half4_t*)(Vb + (size_t)qb * 256);
        float4_t sb = MFMA16(k0, qfb, zero, 0, 0, 0);
        half4_t pb = attn_exps_masked(sb, lsb, r, c);
        ob = MFMA16(pb, v0, ob, 0, 0, 0);
    }
    int pib = wave >> 1;
    if (split == 1) {
        #pragma unroll
        for (int i = 0; i < 4; i++) {
            mrg[pib][i][lane] = oa[i];
            mrg[pib][4 + i][lane] = ob[i];
        }
        mrg[pib][8][lane] = lsa;
        mrg[pib][9][lane] = lsb;
    }
    __syncthreads();
    if (split == 0) {
        #pragma unroll
        for (int i = 0; i < 4; i++) {
            oa[i] += mrg[pib][i][lane];
            ob[i] += mrg[pib][4 + i][lane];
        }
        lsa += mrg[pib][8][lane];
        lsb += mrg[pib][9][lane];
        lsa += __shfl_xor(lsa, 16); lsa += __shfl_xor(lsa, 32);
        lsb += __shfl_xor(lsb, 16); lsb += __shfl_xor(lsb, 32);
        int b = bh >> 3, h = bh & 7;
        #pragma unroll
        for (int reg = 0; reg < 4; reg++) {
            float la = __shfl(lsa, 4 * c + reg);
            float lb = __shfl(lsb, 4 * c + reg);
            Oh[(size_t)(b * Mm + qa * 16 + 4 * c + reg) * 128 + h * 16 + r] = (_Float16)(oa[reg] / la);
            Oh[(size_t)(b * Mm + qb * 16 + 4 * c + reg) * 128 + h * 16 + r] = (_Float16)(ob[reg] / lb);
        }
    }
}

// ---------------- MFMA logits (V=32) + log_softmax + per-row NLL ----------------
__global__ __launch_bounds__(256) void logits_loss_kernel(const _Float16* __restrict__ Xh,
                                                          const _Float16* __restrict__ Wo16,
                                                          const float* __restrict__ bo,
                                                          const int* __restrict__ targets,
                                                          float* __restrict__ logits,
                                                          float* __restrict__ nllBuf) {
    __shared__ _Float16 At[64 * XNS];
    int tid = threadIdx.x;
    int rowb = blockIdx.x * 64;
    #pragma unroll
    for (int it = 0; it < 4; it++) {
        int idx = tid + it * 256;
        int rw = idx >> 4, c8 = (idx & 15) * 8;
        *(half8_t*)(At + rw * XNS + c8) = *(const half8_t*)(Xh + (size_t)(rowb + rw) * 128 + c8);
    }
    __syncthreads();
    int wave = tid >> 6, lane = tid & 63;
    int r = lane & 15, c = lane >> 4;
    int lofs = r * 16 + 4 * c;
    int row0 = rowb + wave * 16;
    half4_t af[8];
    #pragma unroll
    for (int kk = 0; kk < 8; kk++)
        af[kk] = *(const half4_t*)(At + (wave * 16 + r) * XNS + kk * 16 + 4 * c);
    float4_t acc[2];
    acc[0] = (float4_t){0.f, 0.f, 0.f, 0.f};
    acc[1] = (float4_t){0.f, 0.f, 0.f, 0.f};
    #pragma unroll
    for (int kk = 0; kk < 8; kk++) {
        #pragma unroll
        for (int t = 0; t < 2; t++) {
            half4_t wf = *(const half4_t*)(Wo16 + (t * 8 + kk) * 256 + lofs);
            acc[t] = MFMA16(af[kk], wf, acc[t], 0, 0, 0);
        }
    }
    float b0 = bo[r], b1 = bo[r + 16];
    #pragma unroll
    for (int reg = 0; reg < 4; reg++) {
        int row = row0 + 4 * c + reg;
        float l0 = acc[0][reg] + b0;
        float l1 = acc[1][reg] + b1;
        logits[(size_t)row * 32 + r] = l0;
        logits[(size_t)row * 32 + 16 + r] = l1;
        float mx = fmaxf(l0, l1);
        #pragma unroll
        for (int off = 8; off; off >>= 1) mx = fmaxf(mx, __shfl_xor(mx, off));
        float se = __expf(l0 - mx) + __expf(l1 - mx);
        #pragma unroll
        for (int off = 8; off; off >>= 1) se += __shfl_xor(se, off);
        int tgt = targets[row];
        float sel = (tgt & 16) ? l1 : l0;
        float tval = __shfl(sel, (lane & 48) | (tgt & 15));
        if (r == 0) nllBuf[row] = logf(se) + mx - tval;
    }
}

// ---------------- reduce 16384 NLLs -> mean (double accumulation) ----------------
__global__ __launch_bounds__(256) void loss_reduce_kernel(const float* __restrict__ nllBuf,
                                                          float* __restrict__ out) {
    int t = threadIdx.x;
    double s = 0.0;
    #pragma unroll
    for (int i = 0; i < 64; i++) s += (double)nllBuf[t * 64 + i];
    __shared__ double sh[256];
    sh[t] = s;
    __syncthreads();
    for (int off = 128; off; off >>= 1) {
        if (t < off) sh[t] += sh[t + off];
        __syncthreads();
    }
    if (t == 0) out[0] = (float)(sh[0] * (1.0 / (double)BM));
}

extern "C" void kernel_launch(void* const* d_in, const int* in_sizes, int n_in,
                              void* d_out, int out_size, void* d_ws, size_t ws_size,
                              hipStream_t stream) {
    const int*   idx       = (const int*)d_in[0];
    const int*   targets   = (const int*)d_in[1];
    const float* emb       = (const float*)d_in[2];
    const float* rms_scale = (const float*)d_in[3];
    const float* Wq        = (const float*)d_in[4];
    const float* Wk        = (const float*)d_in[5];
    const float* Wv        = (const float*)d_in[6];
    const float* in_w      = (const float*)d_in[7];
    const float* in_b      = (const float*)d_in[8];
    const float* out_pw    = (const float*)d_in[9];
    const float* out_pb    = (const float*)d_in[10];
    const float* lin_w     = (const float*)d_in[11];
    const float* lin_b     = (const float*)d_in[12];
    const float* out_w     = (const float*)d_in[13];
    const float* out_b     = (const float*)d_in[14];
    float* out = (float*)d_out;

    char* base = (char*)d_ws;
    const size_t MB = 1024 * 1024;
    _Float16* xh16  = (_Float16*)base;                 // 0..4MB   gathered x (f16)
    _Float16* xnh   = (_Float16*)(base + 4 * MB);      // 4..8MB   normed x (resid for ep1)
    _Float16* Oh    = (_Float16*)(base + 8 * MB);      // 8..12MB  attn out (f16)
    _Float16* xresh = (_Float16*)(base + 12 * MB);     // 12..16MB residual-2 (f16)
    _Float16* ffoh  = (_Float16*)(base + 16 * MB);     // 16..20MB ffn out (f16)
    _Float16* Qp    = (_Float16*)(base + 20 * MB);     // 20..24MB
    _Float16* Kp    = (_Float16*)(base + 24 * MB);     // 24..28MB
    _Float16* Vp    = (_Float16*)(base + 28 * MB);     // 28..32MB
    float*    cosT  = (float*)(base + 32 * MB);        // 512KB
    float*    sinT  = cosT + Mm * 64;                  // 512KB
    float*    part1 = sinT + Mm * 64;                  // 2048
    float*    part2 = part1 + 2048;                    // 512
    _Float16* Wh    = (_Float16*)(part2 + 512);        // 135168 halves (8 mats + out_w, blocked)
    float*    nllBuf = (float*)(Wh + 135168);          // 64KB

    front_kernel<<<1040 + 2048, 256, 0, stream>>>(Wq, Wk, Wv, in_w, out_pw, lin_w, out_w,
                                                  Wh, cosT, sinT, idx, emb, xh16, part1);

    gemm_qkvproj_kernel<<<BM / 32, 256, 0, stream>>>(xh16, rms_scale, part1,
                                                     Wh, Wh + 3 * 16384, in_b,
                                                     cosT, sinT, xnh, Qp, Kp, Vp);

    attn_kernel<<<4096 / 2, 256, 0, stream>>>(Qp, Kp, Vp, Oh);

    gemm_ep1_kernel<<<BM / 32, 256, 0, stream>>>(Oh, Wh + 6 * 16384, out_pb, xnh, xresh, part2);
    gemm_ep2_kernel<<<BM / 32, 256, 0, stream>>>(xresh, rms_scale, part2, Wh + 7 * 16384, lin_b, ffoh);

    logits_loss_kernel<<<BM / 64, 256, 0, stream>>>(ffoh, Wh + 131072, out_b, targets, out, nllBuf);
    loss_reduce_kernel<<<1, 256, 0, stream>>>(nllBuf, out + (size_t)BM * Vv);
}

// Round 16
// 160.580 us; speedup vs baseline: 1.0421x; 1.0421x over previous
//
#include <hip/hip_runtime.h>
#include <hip/hip_bf16.h>
#include <math.h>

#define Vv   32
#define Dd   128
#define Hh   8
#define Bb   8
#define Mm   2048
#define BM   (Bb*Mm)        // 16384
#define NEL  (BM*Dd)        // 2097152
#define XNS  140            // LDS stride (halves) for 128-col tiles, bank-padded
#define QKS  396            // LDS stride (halves) for 384-col qkv tile, bank-padded

typedef _Float16 half4_t __attribute__((ext_vector_type(4)));
typedef _Float16 half8_t __attribute__((ext_vector_type(8)));
typedef __fp16   fp16x2  __attribute__((ext_vector_type(2)));
typedef float    float4_t __attribute__((ext_vector_type(4)));
#define MFMA16 __builtin_amdgcn_mfma_f32_16x16x16f16

#if __has_builtin(__builtin_amdgcn_exp2f)
__device__ __forceinline__ float fexp2(float x) { return __builtin_amdgcn_exp2f(x); }
#else
__device__ __forceinline__ float fexp2(float x) { return __expf(x * 0.6931471805599453f); }
#endif

// ---------------- front: [blocks 0..1039] weights->blocked f16 + RoPE tables;
//                  [blocks 1040..3087] embedding gather -> f16 + ssq partials ----------------
__global__ __launch_bounds__(256) void front_kernel(const float* __restrict__ Wq,
                                                    const float* __restrict__ Wk,
                                                    const float* __restrict__ Wv,
                                                    const float* __restrict__ in_w,
                                                    const float* __restrict__ out_pw,
                                                    const float* __restrict__ lin_w,
                                                    const float* __restrict__ out_w,
                                                    _Float16* __restrict__ Wh,
                                                    float* __restrict__ cosT,
                                                    float* __restrict__ sinT,
                                                    const int* __restrict__ idx,
                                                    const float* __restrict__ emb,
                                                    _Float16* __restrict__ Xh,
                                                    float* __restrict__ partials) {
    __shared__ float wsum[4];
    if (blockIdx.x < 1040) {
        int gid = blockIdx.x * 256 + threadIdx.x;       // 266240 slots
        if (gid < 135168) {
            const float* src;
            int i;
            if (gid < 131072) {
                int seg = gid >> 14; i = gid & 16383;
                src = seg == 0 ? Wq : seg == 1 ? Wk : seg == 2 ? Wv :
                      seg < 6 ? in_w + (size_t)(seg - 3) * 16384 :
                      seg == 6 ? out_pw : lin_w;
            } else { src = out_w; i = gid - 131072; }   // out_w: 32x128 -> 16 tiles
            int tile = i >> 8, within = i & 255;
            int nt = tile >> 3, kk = tile & 7;
            int r = within >> 4, cc = within & 15;
            Wh[gid] = (_Float16)src[(nt * 16 + r) * 128 + kk * 16 + cc];
        } else {
            int rid = gid - 135168;                     // Mm*64 = 131072
            int i = rid & 63, m = rid >> 6;
            float ex = -2.0f * ((float)i - 1.0f) / 128.0f;
            float basef = expf(ex * 9.210340371976184f);
            float ang = (float)m * basef;
            cosT[rid] = cosf(ang);
            sinT[rid] = sinf(ang);
        }
    } else {
        int blk = blockIdx.x - 1040;                    // 0..2047
        int gid = blk * 256 + threadIdx.x;              // NEL/4
        int token = gid >> 5, t4 = gid & 31;
        float4 x = *(const float4*)(emb + (size_t)idx[token] * 128 + t4 * 4);
        half4_t o;
        o[0] = (_Float16)x.x; o[1] = (_Float16)x.y; o[2] = (_Float16)x.z; o[3] = (_Float16)x.w;
        *(half4_t*)(Xh + (size_t)gid * 4) = o;
        float v = x.x * x.x + x.y * x.y + x.z * x.z + x.w * x.w;
        #pragma unroll
        for (int off = 32; off; off >>= 1) v += __shfl_xor(v, off);
        int lane = threadIdx.x & 63, wave = threadIdx.x >> 6;
        if (lane == 0) wsum[wave] = v;
        __syncthreads();
        if (threadIdx.x == 0) partials[blk] = wsum[0] + wsum[1] + wsum[2] + wsum[3];
    }
}

// ---------------- FUSED: ssq-reduce + normscale + QKV proj + RoPE + in_proj -> Qp/Kp/Vp ----------------
__global__ __launch_bounds__(256) void gemm_qkvproj_kernel(const _Float16* __restrict__ xh,
                                                           const float* __restrict__ scale,
                                                           const float* __restrict__ part1,
                                                           const _Float16* __restrict__ Whqkv,
                                                           const _Float16* __restrict__ Whin,
                                                           const float* __restrict__ in_b,
                                                           const float* __restrict__ cosT,
                                                           const float* __restrict__ sinT,
                                                           _Float16* __restrict__ xnh,
                                                           _Float16* __restrict__ Qp,
                                                           _Float16* __restrict__ Kp,
                                                           _Float16* __restrict__ Vp) {
    __shared__ _Float16 xn[32 * XNS];
    __shared__ _Float16 qkv[32 * QKS];
    __shared__ float wsum0[4];
    int tid = threadIdx.x;
    int row0 = blockIdx.x * 32;
    {
        float v = part1[(row0 >> 11) * 256 + tid];
        #pragma unroll
        for (int off = 32; off; off >>= 1) v += __shfl_xor(v, off);
        if ((tid & 63) == 0) wsum0[tid >> 6] = v;
    }
    __syncthreads();
    float iv = 512.0f / sqrtf(wsum0[0] + wsum0[1] + wsum0[2] + wsum0[3]);
    {
        #pragma unroll
        for (int it = 0; it < 2; it++) {
            int idx = tid + it * 256;
            int rw = idx >> 4, c8 = (idx & 15) * 8;
            int m = (row0 + rw) & (Mm - 1);
            half8_t x8 = *(const half8_t*)(xh + (size_t)(row0 + rw) * 128 + c8);
            const float* sp = scale + (size_t)m * 128 + c8;
            float4 s0 = *(const float4*)sp;
            float4 s1 = *(const float4*)(sp + 4);
            half8_t o8;
            o8[0] = (_Float16)((float)x8[0] * iv * s0.x);
            o8[1] = (_Float16)((float)x8[1] * iv * s0.y);
            o8[2] = (_Float16)((float)x8[2] * iv * s0.z);
            o8[3] = (_Float16)((float)x8[3] * iv * s0.w);
            o8[4] = (_Float16)((float)x8[4] * iv * s1.x);
            o8[5] = (_Float16)((float)x8[5] * iv * s1.y);
            o8[6] = (_Float16)((float)x8[6] * iv * s1.z);
            o8[7] = (_Float16)((float)x8[7] * iv * s1.w);
            *(half8_t*)(xn + rw * XNS + c8) = o8;
            *(half8_t*)(xnh + (size_t)(row0 + rw) * 128 + c8) = o8;
        }
    }
    __syncthreads();
    int wave = tid >> 6, lane = tid & 63;
    int r = lane & 15, c = lane >> 4;
    int lofs = r * 16 + 4 * c;
    int nb = wave * 96;
    int nb16 = wave * 6;
    {
        half4_t af[2][8];
        #pragma unroll
        for (int rt = 0; rt < 2; rt++)
            #pragma unroll
            for (int kk = 0; kk < 8; kk++)
                af[rt][kk] = *(const half4_t*)(xn + (rt * 16 + r) * XNS + kk * 16 + 4 * c);
        float4_t acc[2][6];
        #pragma unroll
        for (int rt = 0; rt < 2; rt++)
            #pragma unroll
            for (int t = 0; t < 6; t++) acc[rt][t] = (float4_t){0.f, 0.f, 0.f, 0.f};
        #pragma unroll
        for (int kk = 0; kk < 8; kk++) {
            half4_t wf[6];
            #pragma unroll
            for (int t = 0; t < 6; t++)
                wf[t] = *(const half4_t*)(Whqkv + ((nb16 + t) * 8 + kk) * 256 + lofs);
            #pragma unroll
            for (int t = 0; t < 6; t++) {
                acc[0][t] = MFMA16(af[0][kk], wf[t], acc[0][t], 0, 0, 0);
                acc[1][t] = MFMA16(af[1][kk], wf[t], acc[1][t], 0, 0, 0);
            }
        }
        #pragma unroll
        for (int rt = 0; rt < 2; rt++) {
            #pragma unroll
            for (int t = 0; t < 6; t++) {
                int n = nb + t * 16 + r;
                int ci = (n & 127) >> 1;
                #pragma unroll
                for (int reg = 0; reg < 4; reg++) {
                    int m2 = (row0 + rt * 16 + 4 * c + reg) & (Mm - 1);
                    float v = acc[rt][t][reg];
                    float vp = __shfl_xor(v, 1);     // pair column n^1 lives in lane^1
                    float cs = cosT[m2 * 64 + ci], sn = sinT[m2 * 64 + ci];
                    v = (n & 1) ? (-vp * sn + v * cs) : (v * cs + vp * sn);
                    qkv[(rt * 16 + 4 * c + reg) * QKS + n] = (_Float16)v;
                }
            }
        }
    }
    __syncthreads();
    {
        int seg_lo = nb >> 7;
        int seg_hi = (nb + 80) >> 7;
        half4_t aql[2][8], aqh[2][8];
        #pragma unroll
        for (int rt = 0; rt < 2; rt++)
            #pragma unroll
            for (int kk = 0; kk < 8; kk++) {
                aql[rt][kk] = *(const half4_t*)(qkv + (rt * 16 + r) * QKS + seg_lo * 128 + kk * 16 + 4 * c);
                aqh[rt][kk] = *(const half4_t*)(qkv + (rt * 16 + r) * QKS + seg_hi * 128 + kk * 16 + 4 * c);
            }
        float4_t acc[2][6];
        #pragma unroll
        for (int rt = 0; rt < 2; rt++)
            #pragma unroll
            for (int t = 0; t < 6; t++) acc[rt][t] = (float4_t){0.f, 0.f, 0.f, 0.f};
        #pragma unroll
        for (int kk = 0; kk < 8; kk++) {
            half4_t wf[6];
            #pragma unroll
            for (int t = 0; t < 6; t++) {
                int colg = nb + t * 16;
                int seg = colg >> 7;
                int ntl = (colg & 127) >> 4;
                wf[t] = *(const half4_t*)(Whin + ((seg * 8 + ntl) * 8 + kk) * 256 + lofs);
            }
            #pragma unroll
            for (int t = 0; t < 6; t++) {
                int seg = (nb + t * 16) >> 7;
                acc[0][t] = MFMA16(seg == seg_lo ? aql[0][kk] : aqh[0][kk], wf[t], acc[0][t], 0, 0, 0);
                acc[1][t] = MFMA16(seg == seg_lo ? aql[1][kk] : aqh[1][kk], wf[t], acc[1][t], 0, 0, 0);
            }
        }
        int bb = row0 >> 11;
        #pragma unroll
        for (int rt = 0; rt < 2; rt++) {
            int t16 = ((row0 + rt * 16) & 2047) >> 4;
            #pragma unroll
            for (int t = 0; t < 6; t++) {
                int colg = nb + t * 16;
                int seg = colg >> 7;
                int h = (colg & 127) >> 4;
                size_t tb = ((size_t)(bb * 8 + h) * 128 + t16) * 256;
                float bv = in_b[colg + r];
                _Float16* dst = seg == 0 ? Qp : seg == 1 ? Kp : Vp;
                #pragma unroll
                for (int reg = 0; reg < 4; reg++) {
                    float v = acc[rt][t][reg] + bv;
                    int key = 4 * c + reg;
                    if (seg < 2) dst[tb + key * 16 + r] = (_Float16)v;   // [token][d=r]
                    else         dst[tb + r * 16 + key] = (_Float16)v;   // [d=r][token]
                }
            }
        }
    }
}

// ---------------- out_proj: Oh f16 @ W^T + bias + resid(xnh) -> xresh f16, ssq partials ----------------
__global__ __launch_bounds__(256) void gemm_ep1_kernel(const _Float16* __restrict__ Oh,
                                                       const _Float16* __restrict__ W6,
                                                       const float* __restrict__ bias,
                                                       const _Float16* __restrict__ xnh,
                                                       _Float16* __restrict__ xresh,
                                                       float* __restrict__ partials) {
    __shared__ _Float16 At[32 * XNS];
    int tid = threadIdx.x;
    int row0 = blockIdx.x * 32;
    #pragma unroll
    for (int it = 0; it < 2; it++) {
        int idx = tid + it * 256;
        int rw = idx >> 4, c8 = (idx & 15) * 8;
        *(half8_t*)(At + rw * XNS + c8) = *(const half8_t*)(Oh + (size_t)(row0 + rw) * 128 + c8);
    }
    __syncthreads();
    int wave = tid >> 6, lane = tid & 63;
    int r = lane & 15, c = lane >> 4;
    int lofs = r * 16 + 4 * c;
    int n0 = wave * 32;
    half4_t af[2][8];
    #pragma unroll
    for (int rt = 0; rt < 2; rt++)
        #pragma unroll
        for (int kk = 0; kk < 8; kk++)
            af[rt][kk] = *(const half4_t*)(At + (rt * 16 + r) * XNS + kk * 16 + 4 * c);
    float4_t acc[2][2];
    #pragma unroll
    for (int rt = 0; rt < 2; rt++) {
        acc[rt][0] = (float4_t){0.f, 0.f, 0.f, 0.f};
        acc[rt][1] = (float4_t){0.f, 0.f, 0.f, 0.f};
    }
    #pragma unroll
    for (int kk = 0; kk < 8; kk++) {
        half4_t wf[2];
        wf[0] = *(const half4_t*)(W6 + ((wave * 2 + 0) * 8 + kk) * 256 + lofs);
        wf[1] = *(const half4_t*)(W6 + ((wave * 2 + 1) * 8 + kk) * 256 + lofs);
        #pragma unroll
        for (int t = 0; t < 2; t++) {
            acc[0][t] = MFMA16(af[0][kk], wf[t], acc[0][t], 0, 0, 0);
            acc[1][t] = MFMA16(af[1][kk], wf[t], acc[1][t], 0, 0, 0);
        }
    }
    float lssq = 0.f;
    #pragma unroll
    for (int rt = 0; rt < 2; rt++) {
        #pragma unroll
        for (int t = 0; t < 2; t++) {
            int n = n0 + t * 16 + r;
            float bv = bias[n];
            #pragma unroll
            for (int reg = 0; reg < 4; reg++) {
                int row = row0 + rt * 16 + 4 * c + reg;
                float v = acc[rt][t][reg] + bv + (float)xnh[(size_t)row * 128 + n];
                lssq += v * v;
                xresh[(size_t)row * 128 + n] = (_Float16)v;
            }
        }
    }
    #pragma unroll
    for (int off = 32; off; off >>= 1) lssq += __shfl_xor(lssq, off);
    __shared__ float wsum[4];
    if (lane == 0) wsum[wave] = lssq;
    __syncthreads();
    if (tid == 0) partials[blockIdx.x] = wsum[0] + wsum[1] + wsum[2] + wsum[3];
}

// ---------------- FUSED FFN: ssq-reduce + normscale(xresh) + GEMM + relu + resid -> ffoh f16 ----------------
__global__ __launch_bounds__(256) void gemm_ep2_kernel(const _Float16* __restrict__ xresh,
                                                       const float* __restrict__ scale,
                                                       const float* __restrict__ part2,
                                                       const _Float16* __restrict__ W7,
                                                       const float* __restrict__ bias,
                                                       _Float16* __restrict__ ffoh) {
    __shared__ _Float16 At[32 * XNS];
    int tid = threadIdx.x;
    int row0 = blockIdx.x * 32;
    float pv = part2[(row0 >> 11) * 64 + (tid & 63)];
    #pragma unroll
    for (int off = 32; off; off >>= 1) pv += __shfl_xor(pv, off);
    float iv = 512.0f / sqrtf(pv);
    #pragma unroll
    for (int it = 0; it < 2; it++) {
        int idx = tid + it * 256;
        int rw = idx >> 4, c8 = (idx & 15) * 8;
        int m = (row0 + rw) & (Mm - 1);
        half8_t x8 = *(const half8_t*)(xresh + (size_t)(row0 + rw) * 128 + c8);
        const float* sp = scale + (size_t)m * 128 + c8;
        float4 s0 = *(const float4*)sp;
        float4 s1 = *(const float4*)(sp + 4);
        half8_t o8;
        o8[0] = (_Float16)((float)x8[0] * iv * s0.x);
        o8[1] = (_Float16)((float)x8[1] * iv * s0.y);
        o8[2] = (_Float16)((float)x8[2] * iv * s0.z);
        o8[3] = (_Float16)((float)x8[3] * iv * s0.w);
        o8[4] = (_Float16)((float)x8[4] * iv * s1.x);
        o8[5] = (_Float16)((float)x8[5] * iv * s1.y);
        o8[6] = (_Float16)((float)x8[6] * iv * s1.z);
        o8[7] = (_Float16)((float)x8[7] * iv * s1.w);
        *(half8_t*)(At + rw * XNS + c8) = o8;
    }
    __syncthreads();
    int wave = tid >> 6, lane = tid & 63;
    int r = lane & 15, c = lane >> 4;
    int lofs = r * 16 + 4 * c;
    int n0 = wave * 32;
    half4_t af[2][8];
    #pragma unroll
    for (int rt = 0; rt < 2; rt++)
        #pragma unroll
        for (int kk = 0; kk < 8; kk++)
            af[rt][kk] = *(const half4_t*)(At + (rt * 16 + r) * XNS + kk * 16 + 4 * c);
    float4_t acc[2][2];
    #pragma unroll
    for (int rt = 0; rt < 2; rt++) {
        acc[rt][0] = (float4_t){0.f, 0.f, 0.f, 0.f};
        acc[rt][1] = (float4_t){0.f, 0.f, 0.f, 0.f};
    }
    #pragma unroll
    for (int kk = 0; kk < 8; kk++) {
        half4_t wf[2];
        wf[0] = *(const half4_t*)(W7 + ((wave * 2 + 0) * 8 + kk) * 256 + lofs);
        wf[1] = *(const half4_t*)(W7 + ((wave * 2 + 1) * 8 + kk) * 256 + lofs);
        #pragma unroll
        for (int t = 0; t < 2; t++) {
            acc[0][t] = MFMA16(af[0][kk], wf[t], acc[0][t], 0, 0, 0);
            acc[1][t] = MFMA16(af[1][kk], wf[t], acc[1][t], 0, 0, 0);
        }
    }
    #pragma unroll
    for (int rt = 0; rt < 2; rt++) {
        #pragma unroll
        for (int t = 0; t < 2; t++) {
            int n = n0 + t * 16 + r;
            float bv = bias[n];
            #pragma unroll
            for (int reg = 0; reg < 4; reg++) {
                int row = row0 + rt * 16 + 4 * c + reg;
                float v = fmaxf(acc[rt][t][reg] + bv, 0.f) + (float)xresh[(size_t)row * 128 + n];
                ffoh[(size_t)row * 128 + n] = (_Float16)v;
            }
        }
    }
}

// ---------------- attention helpers (plain-add denominator) ----------------
__device__ __forceinline__ half4_t attn_exps(float4_t st, float& ls) {
    float p0 = fexp2(st[0]), p1 = fexp2(st[1]);
    float p2 = fexp2(st[2]), p3 = fexp2(st[3]);
    ls += (p0 + p1) + (p2 + p3);
    fp16x2 lo = __builtin_amdgcn_cvt_pkrtz(p0, p1);
    fp16x2 hi = __builtin_amdgcn_cvt_pkrtz(p2, p3);
    half4_t pf;
    pf[0] = (_Float16)lo[0]; pf[1] = (_Float16)lo[1];
    pf[2] = (_Float16)hi[0]; pf[3] = (_Float16)hi[1];
    return pf;
}
__device__ __forceinline__ half4_t attn_exps_masked(float4_t st, float& ls, int r, int c) {
    float p0 = (4 * c + 0 <= r) ? fexp2(st[0]) : 0.f;
    float p1 = (4 * c + 1 <= r) ? fexp2(st[1]) : 0.f;
    float p2 = (4 * c + 2 <= r) ? fexp2(st[2]) : 0.f;
    float p3 = (4 * c + 3 <= r) ? fexp2(st[3]) : 0.f;
    ls += (p0 + p1) + (p2 + p3);
    fp16x2 lo = __builtin_amdgcn_cvt_pkrtz(p0, p1);
    fp16x2 hi = __builtin_amdgcn_cvt_pkrtz(p2, p3);
    half4_t pf;
    pf[0] = (_Float16)lo[0]; pf[1] = (_Float16)lo[1];
    pf[2] = (_Float16)hi[0]; pf[3] = (_Float16)hi[1];
    return pf;
}

// ---------------- MFMA flash attention: paired q-tiles + split-K (2 waves/pair) ----------------
// R13 structure (no manual unroll — compiler schedules the tight loop best).
__global__ __launch_bounds__(256) void attn_kernel(const _Float16* __restrict__ Qp,
                                                   const _Float16* __restrict__ Kp,
                                                   const _Float16* __restrict__ Vp,
                                                   _Float16* __restrict__ Oh) {
    __shared__ float mrg[2][10][64];
    int wave = threadIdx.x >> 6, lane = threadIdx.x & 63;
    int pair = blockIdx.x * 2 + (wave >> 1);         // 0..4095
    int split = wave & 1;
    int qa = pair & 63, bh = pair >> 6, qb = 127 - qa;
    int r = lane & 15, c = lane >> 4;
    int lofs = r * 16 + 4 * c;
    const _Float16* Kb = Kp + (size_t)bh * 32768 + lofs;
    const _Float16* Vb = Vp + (size_t)bh * 32768 + lofs;
    const _Float16* Qb = Qp + (size_t)bh * 32768 + lofs;
    half4_t qfa = *(const half4_t*)(Qb + qa * 256);
    half4_t qfb = *(const half4_t*)(Qb + qb * 256);
    const _Float16 qscale = (_Float16)0.36067376f;   // 0.25 * log2(e)
    qfa *= qscale;
    qfb *= qscale;
    float4_t zero = {0.f, 0.f, 0.f, 0.f};
    float4_t oa = zero, ob = zero;
    float lsa = 0.f, lsb = 0.f;

    for (int kt = split; kt < qa; kt += 2) {
        half4_t k0 = *(const half4_t*)(Kb + (size_t)kt * 256);
        half4_t v0 = *(const half4_t*)(Vb + (size_t)kt * 256);
        float4_t sa = MFMA16(k0, qfa, zero, 0, 0, 0);
        float4_t sb = MFMA16(k0, qfb, zero, 0, 0, 0);
        half4_t pa = attn_exps(sa, lsa);
        half4_t pb = attn_exps(sb, lsb);
        oa = MFMA16(pa, v0, oa, 0, 0, 0);
        ob = MFMA16(pb, v0, ob, 0, 0, 0);
    }
    if ((qa & 1) == split) {                         // tile qa: masked for a, full for b
        half4_t k0 = *(const half4_t*)(Kb + (size_t)qa * 256);
        half4_t v0 = *(const half4_t*)(Vb + (size_t)qa * 256);
        float4_t sa = MFMA16(k0, qfa, zero, 0, 0, 0);
        float4_t sb = MFMA16(k0, qfb, zero, 0, 0, 0);
        half4_t pa = attn_exps_masked(sa, lsa, r, c);
        half4_t pb = attn_exps(sb, lsb);
        oa = MFMA16(pa, v0, oa, 0, 0, 0);
        ob = MFMA16(pb, v0, ob, 0, 0, 0);
    }
    {
        int s = qa + 1;
        if ((s & 1) != split) s++;
        for (int kt = s; kt < qb; kt += 2) {
            half4_t k0 = *(const half4_t*)(Kb + (size_t)kt * 256);
            half4_t v0 = *(const half4_t*)(Vb + (size_t)kt * 256);
            float4_t sb = MFMA16(k0, qfb, zero, 0, 0, 0);
            half4_t pb = attn_exps(sb, lsb);
            ob = MFMA16(pb, v0, ob, 0, 0, 0);
        }
    }
    if ((qb & 1) == split) {                         // tile qb: masked for b
        half4_t k0 = *(const half4_t*)(Kb + (size_t)qb * 256);
        half4_t v0 = *(const half4_t*)(Vb + (size_t)qb * 256);
        float4_t sb = MFMA16(k0, qfb, zero, 0, 0, 0);
        half4_t pb = attn_exps_masked(sb, lsb, r, c);
        ob = MFMA16(pb, v0, ob, 0, 0, 0);
    }
    int pib = wave >> 1;
    if (split == 1) {
        #pragma unroll
        for (int i = 0; i < 4; i++) {
            mrg[pib][i][lane] = oa[i];
            mrg[pib][4 + i][lane] = ob[i];
        }
        mrg[pib][8][lane] = lsa;
        mrg[pib][9][lane] = lsb;
    }
    __syncthreads();
    if (split == 0) {
        #pragma unroll
        for (int i = 0; i < 4; i++) {
            oa[i] += mrg[pib][i][lane];
            ob[i] += mrg[pib][4 + i][lane];
        }
        lsa += mrg[pib][8][lane];
        lsb += mrg[pib][9][lane];
        lsa += __shfl_xor(lsa, 16); lsa += __shfl_xor(lsa, 32);
        lsb += __shfl_xor(lsb, 16); lsb += __shfl_xor(lsb, 32);
        int b = bh >> 3, h = bh & 7;
        #pragma unroll
        for (int reg = 0; reg < 4; reg++) {
            float la = __shfl(lsa, 4 * c + reg);
            float lb = __shfl(lsb, 4 * c + reg);
            Oh[(size_t)(b * Mm + qa * 16 + 4 * c + reg) * 128 + h * 16 + r] = (_Float16)(oa[reg] / la);
            Oh[(size_t)(b * Mm + qb * 16 + 4 * c + reg) * 128 + h * 16 + r] = (_Float16)(ob[reg] / lb);
        }
    }
}

// ---------------- MFMA logits (V=32) + log_softmax + per-row NLL ----------------
__global__ __launch_bounds__(256) void logits_loss_kernel(const _Float16* __restrict__ Xh,
                                                          const _Float16* __restrict__ Wo16,
                                                          const float* __restrict__ bo,
                                                          const int* __restrict__ targets,
                                                          float* __restrict__ logits,
                                                          float* __restrict__ nllBuf) {
    __shared__ _Float16 At[64 * XNS];
    int tid = threadIdx.x;
    int rowb = blockIdx.x * 64;
    #pragma unroll
    for (int it = 0; it < 4; it++) {
        int idx = tid + it * 256;
        int rw = idx >> 4, c8 = (idx & 15) * 8;
        *(half8_t*)(At + rw * XNS + c8) = *(const half8_t*)(Xh + (size_t)(rowb + rw) * 128 + c8);
    }
    __syncthreads();
    int wave = tid >> 6, lane = tid & 63;
    int r = lane & 15, c = lane >> 4;
    int lofs = r * 16 + 4 * c;
    int row0 = rowb + wave * 16;
    half4_t af[8];
    #pragma unroll
    for (int kk = 0; kk < 8; kk++)
        af[kk] = *(const half4_t*)(At + (wave * 16 + r) * XNS + kk * 16 + 4 * c);
    float4_t acc[2];
    acc[0] = (float4_t){0.f, 0.f, 0.f, 0.f};
    acc[1] = (float4_t){0.f, 0.f, 0.f, 0.f};
    #pragma unroll
    for (int kk = 0; kk < 8; kk++) {
        #pragma unroll
        for (int t = 0; t < 2; t++) {
            half4_t wf = *(const half4_t*)(Wo16 + (t * 8 + kk) * 256 + lofs);
            acc[t] = MFMA16(af[kk], wf, acc[t], 0, 0, 0);
        }
    }
    float b0 = bo[r], b1 = bo[r + 16];
    #pragma unroll
    for (int reg = 0; reg < 4; reg++) {
        int row = row0 + 4 * c + reg;
        float l0 = acc[0][reg] + b0;
        float l1 = acc[1][reg] + b1;
        logits[(size_t)row * 32 + r] = l0;
        logits[(size_t)row * 32 + 16 + r] = l1;
        float mx = fmaxf(l0, l1);
        #pragma unroll
        for (int off = 8; off; off >>= 1) mx = fmaxf(mx, __shfl_xor(mx, off));
        float se = __expf(l0 - mx) + __expf(l1 - mx);
        #pragma unroll
        for (int off = 8; off; off >>= 1) se += __shfl_xor(se, off);
        int tgt = targets[row];
        float sel = (tgt & 16) ? l1 : l0;
        float tval = __shfl(sel, (lane & 48) | (tgt & 15));
        if (r == 0) nllBuf[row] = logf(se) + mx - tval;
    }
}

// ---------------- reduce 16384 NLLs -> mean (double accumulation) ----------------
__global__ __launch_bounds__(256) void loss_reduce_kernel(const float* __restrict__ nllBuf,
                                                          float* __restrict__ out) {
    int t = threadIdx.x;
    double s = 0.0;
    #pragma unroll
    for (int i = 0; i < 64; i++) s += (double)nllBuf[t * 64 + i];
    __shared__ double sh[256];
    sh[t] = s;
    __syncthreads();
    for (int off = 128; off; off >>= 1) {
        if (t < off) sh[t] += sh[t + off];
        __syncthreads();
    }
    if (t == 0) out[0] = (float)(sh[0] * (1.0 / (double)BM));
}

extern "C" void kernel_launch(void* const* d_in, const int* in_sizes, int n_in,
                              void* d_out, int out_size, void* d_ws, size_t ws_size,
                              hipStream_t stream) {
    const int*   idx       = (const int*)d_in[0];
    const int*   targets   = (const int*)d_in[1];
    const float* emb       = (const float*)d_in[2];
    const float* rms_scale = (const float*)d_in[3];
    const float* Wq        = (const float*)d_in[4];
    const float* Wk        = (const float*)d_in[5];
    const float* Wv        = (const float*)d_in[6];
    const float* in_w      = (const float*)d_in[7];
    const float* in_b      = (const float*)d_in[8];
    const float* out_pw    = (const float*)d_in[9];
    const float* out_pb    = (const float*)d_in[10];
    const float* lin_w     = (const float*)d_in[11];
    const float* lin_b     = (const float*)d_in[12];
    const float* out_w     = (const float*)d_in[13];
    const float* out_b     = (const float*)d_in[14];
    float* out = (float*)d_out;

    char* base = (char*)d_ws;
    const size_t MB = 1024 * 1024;
    _Float16* xh16  = (_Float16*)base;                 // 0..4MB   gathered x (f16)
    _Float16* xnh   = (_Float16*)(base + 4 * MB);      // 4..8MB   normed x (resid for ep1)
    _Float16* Oh    = (_Float16*)(base + 8 * MB);      // 8..12MB  attn out (f16)
    _Float16* xresh = (_Float16*)(base + 12 * MB);     // 12..16MB residual-2 (f16)
    _Float16* ffoh  = (_Float16*)(base + 16 * MB);     // 16..20MB ffn out (f16)
    _Float16* Qp    = (_Float16*)(base + 20 * MB);     // 20..24MB
    _Float16* Kp    = (_Float16*)(base + 24 * MB);     // 24..28MB
    _Float16* Vp    = (_Float16*)(base + 28 * MB);     // 28..32MB
    float*    cosT  = (float*)(base + 32 * MB);        // 512KB
    float*    sinT  = cosT + Mm * 64;                  // 512KB
    float*    part1 = sinT + Mm * 64;                  // 2048
    float*    part2 = part1 + 2048;                    // 512
    _Float16* Wh    = (_Float16*)(part2 + 512);        // 135168 halves (8 mats + out_w, blocked)
    float*    nllBuf = (float*)(Wh + 135168);          // 64KB

    front_kernel<<<1040 + 2048, 256, 0, stream>>>(Wq, Wk, Wv, in_w, out_pw, lin_w, out_w,
                                                  Wh, cosT, sinT, idx, emb, xh16, part1);

    gemm_qkvproj_kernel<<<BM / 32, 256, 0, stream>>>(xh16, rms_scale, part1,
                                                     Wh, Wh + 3 * 16384, in_b,
                                                     cosT, sinT, xnh, Qp, Kp, Vp);

    attn_kernel<<<4096 / 2, 256, 0, stream>>>(Qp, Kp, Vp, Oh);

    gemm_ep1_kernel<<<BM / 32, 256, 0, stream>>>(Oh, Wh + 6 * 16384, out_pb, xnh, xresh, part2);
    gemm_ep2_kernel<<<BM / 32, 256, 0, stream>>>(xresh, rms_scale, part2, Wh + 7 * 16384, lin_b, ffoh);

    logits_loss_kernel<<<BM / 64, 256, 0, stream>>>(ffoh, Wh + 131072, out_b, targets, out, nllBuf);
    loss_reduce_kernel<<<1, 256, 0, stream>>>(nllBuf, out + (size_t)BM * Vv);
}